// Round 3
// baseline (332.153 us; speedup 1.0000x reference)
//
#include <hip/hip_runtime.h>
#include <hip/hip_bf16.h>

// FourierKANLayer: N=4096, D_IN=512, D_OUT=512, G=32
// y = [cos/sin(k*LN(x)) features] @ W + bias  == GEMM M=4096,N=512,K=32768 (bf16 MFMA)
// R10: A-operand never touches LDS. Each lane computes its own MFMA A-fragment
//      in registers via Chebyshev recurrence from float4 seeds {c1,s1,c16,s16}.
//      k-slice remap (applied to A AND B): seg(lq,h) = (lq>>1)*4+(lq&1)*2+h so a
//      lane's 16 k-values = 16 consecutive harmonics of ONE dim. LDS = B ring
//      only (3x16KB = 48KB), gl_lds depth-2 prefetch, counted vmcnt(8), one raw
//      barrier/iter. Pre-kernel fuses LN-stats + seed-gen + W-cast (3 launches).
// ws layout: [0,32MB)   csT2 float4[512][4096] = {cos,sin,cos16,sin16} seeds
//            [32MB,64MB) bf16 weights [2][512][16384] K-major (32 MiB exact)
//            [64MB,80MB) bf16 split-K partials [4][4096][512] (16 MiB)

#define N_ROWS 4096
#define D_IN   512
#define D_OUT  512
#define KT     16384   // per-trig K = D_IN*G
#define BM 128
#define BN 128
#define SPLITK 4

typedef short short8 __attribute__((ext_vector_type(8)));
typedef float float4v __attribute__((ext_vector_type(4)));

__device__ inline unsigned int pack2bf(float a, float b) {
    __hip_bfloat162 h = __float22bfloat162_rn(make_float2(a, b));
    union { __hip_bfloat162 h; unsigned int u; } cv;
    cv.h = h;
    return cv.u;
}

__device__ inline unsigned short bf16_1(float a) {
    union { float f; unsigned int u; } cv;
    cv.f = a;
    unsigned int r = (cv.u + 0x7fff + ((cv.u >> 16) & 1)) >> 16;  // RN-even
    return (unsigned short)r;
}

// ---- kernel 1: fused LN stats + sincos seeds + doubling ladder + W cast ----
// 256 blocks x 256 thr; block owns 16 rows. Phase A: load x tile -> LDS (pad 516
// keeps 16B align, 2-way banks), per-row stats via 16-lane shfl_xor. Phase B:
// normalize + __sincosf + 4 doublings -> csT2[dim][row] = {c1,s1,c16,s16}
// (coalesced 16-row float4 bursts). Phase C: grid-strided W fp32->bf16 cast.
__global__ __launch_bounds__(256) void pre_kernel(const float* __restrict__ x,
        const float* __restrict__ lnw, const float* __restrict__ lnb,
        const float* __restrict__ fc, float4* __restrict__ csT2,
        unsigned short* __restrict__ Wb) {
    __shared__ __align__(16) float xs[16 * 516];
    __shared__ float2 murs[16];
    const int t = threadIdx.x;
    const int r0 = blockIdx.x * 16;
    {
        const int row = t >> 4, tq = t & 15;
        const float* xr = x + (size_t)(r0 + row) * D_IN;
        float s = 0.f, q = 0.f;
        #pragma unroll
        for (int k = 0; k < 8; ++k) {
            float4 v = *(const float4*)(xr + tq * 4 + k * 64);
            *(float4*)&xs[row * 516 + tq * 4 + k * 64] = v;
            s += v.x + v.y + v.z + v.w;
            q += v.x * v.x + v.y * v.y + v.z * v.z + v.w * v.w;
        }
        #pragma unroll
        for (int off = 8; off > 0; off >>= 1) {
            s += __shfl_xor(s, off, 16);
            q += __shfl_xor(q, off, 16);
        }
        if (tq == 0) {
            float mu = s * (1.f / D_IN);
            float var = q * (1.f / D_IN) - mu * mu;
            murs[row] = make_float2(mu, rsqrtf(var + 1e-5f));
        }
    }
    __syncthreads();
    {
        const int brow = t & 15, dimg = t >> 4;
        const float2 mr = murs[brow];
        #pragma unroll 4
        for (int j = 0; j < 32; ++j) {
            const int dim = j * 16 + dimg;
            float xv = xs[brow * 516 + dim];
            float xn = (xv - mr.x) * mr.y * lnw[dim] + lnb[dim];
            float s1, c1;
            __sincosf(xn, &s1, &c1);
            float k2, c2, s2, c4, s4, c8, s8, c16, s16;
            k2 = c1 + c1; c2  = __builtin_fmaf(k2, c1, -1.f); s2  = k2 * s1;
            k2 = c2 + c2; c4  = __builtin_fmaf(k2, c2, -1.f); s4  = k2 * s2;
            k2 = c4 + c4; c8  = __builtin_fmaf(k2, c4, -1.f); s8  = k2 * s4;
            k2 = c8 + c8; c16 = __builtin_fmaf(k2, c8, -1.f); s16 = k2 * s8;
            csT2[(size_t)dim * N_ROWS + r0 + brow] = make_float4(c1, s1, c16, s16);
        }
    }
    {   // W cast: 16.78M floats = 256 blk x 256 thr x 8 x 32
        size_t e = ((size_t)blockIdx.x * 256 + t) * 8;
        for (int it2 = 0; it2 < 32; ++it2, e += (size_t)256 * 256 * 8) {
            const float4* in = (const float4*)(fc + e);
            float4 a = in[0], c = in[1];
            uint4 o;
            o.x = pack2bf(a.x, a.y);
            o.y = pack2bf(a.z, a.w);
            o.z = pack2bf(c.x, c.y);
            o.w = pack2bf(c.z, c.w);
            *(uint4*)(Wb + e) = o;
        }
    }
}

__device__ inline void gl_lds16(const unsigned short* gsrc, unsigned short* ldst) {
    __builtin_amdgcn_global_load_lds(
        (const __attribute__((address_space(1))) unsigned int*)gsrc,
        (__attribute__((address_space(3))) unsigned int*)ldst, 16, 0, 0);
}

// ---- in-register A-fragment: 16 consecutive harmonics of one dim ----
// even lq: g=1..16 from (1,c1)/(0,s1); odd lq: g=17..32 from (c16,c17)/(s16,s17).
// Recurrence v_{g+1} = 2c1*v_g - v_{g-1} holds for both cos and sin chains.
template<bool SIN>
__device__ __forceinline__ void make_af(float4 sd, bool oddlq,
                                        short8& a0, short8& a1) {
    const float c1 = sd.x, s1 = sd.y, c16 = sd.z, s16 = sd.w;
    const float k2 = c1 + c1;
    float prev, cur;
    if (SIN) {
        float tt = s16 * c1;
        float s17 = __builtin_fmaf(c16, s1, tt);   // sin17 = s16*c1 + c16*s1
        prev = oddlq ? s16 : 0.f;
        cur  = oddlq ? s17 : s1;
    } else {
        float tt = s16 * s1;
        float c17 = __builtin_fmaf(c16, c1, -tt);  // cos17 = c16*c1 - s16*s1
        prev = oddlq ? c16 : 1.f;
        cur  = oddlq ? c17 : c1;
    }
    union { unsigned int u[8]; short8 s8v[2]; } U;
    float p = prev, c = cur;
    #pragma unroll
    for (int d = 0; d < 8; ++d) {
        float n1 = __builtin_fmaf(k2, c, -p);
        U.u[d] = pack2bf(c, n1);
        float n2 = __builtin_fmaf(k2, n1, -c);
        p = n1;
        c = n2;
    }
    a0 = U.s8v[0];
    a1 = U.s8v[1];
}

// ---- one K-iteration: exactly 8 VMEM ops issued (4 gl_lds + 4 seed loads),
// so the trailing vmcnt(8) fence drains everything older regardless of
// within-iter scheduling order. ----
template<bool SIN, bool PF, bool LDSEED>
__device__ __forceinline__ void gemm_step(int it, int rd, int wr,
        unsigned short (*Bs)[BN * 64], const unsigned short* Bg0, int wv,
        const float4* const (&sb)[4], float4 (&sdU)[4], float4 (&sdL)[4],
        int bBase, bool oddlq, float4v (&acc)[4][4]) {
    if (PF) {   // B(it+2) -> Bs[wr]
        const int in = it + 2;
        const unsigned short* gb =
            Bg0 + (size_t)(in >> 6) * D_OUT * KT + (in & 63) * 64;
        unsigned short* ldst = &Bs[wr][(wv * 4) * 512];
        #pragma unroll
        for (int j = 0; j < 4; ++j)
            gl_lds16(gb + (size_t)(j * 8) * KT, ldst + j * 512);
    }
    if (LDSEED) {   // seeds(it+1); dims repeat across the two trig halves (&63)
        #pragma unroll
        for (int tm = 0; tm < 4; ++tm)
            sdL[tm] = sb[tm][(size_t)((it + 1) & 63) * 8192];
    }
    const unsigned short* Bp = Bs[rd];
    short8 bf0[4], bf1[4];
    #pragma unroll
    for (int tn = 0; tn < 4; ++tn) {
        bf0[tn] = *(const short8*)&Bp[bBase + tn * 1024];
        bf1[tn] = *(const short8*)&Bp[bBase + tn * 1024 + 64];
    }
    __builtin_amdgcn_s_setprio(1);
    #pragma unroll
    for (int tm = 0; tm < 4; ++tm) {
        short8 a0, a1;
        make_af<SIN>(sdU[tm], oddlq, a0, a1);
        #pragma unroll
        for (int tn = 0; tn < 4; ++tn)
            acc[tm][tn] = __builtin_amdgcn_mfma_f32_16x16x32_bf16(
                a0, bf0[tn], acc[tm][tn], 0, 0, 0);
        #pragma unroll
        for (int tn = 0; tn < 4; ++tn)
            acc[tm][tn] = __builtin_amdgcn_mfma_f32_16x16x32_bf16(
                a1, bf1[tn], acc[tm][tn], 0, 0, 0);
    }
    __builtin_amdgcn_s_setprio(0);
}

#define FENCE8() do { asm volatile("s_waitcnt vmcnt(8)" ::: "memory"); \
                      __builtin_amdgcn_s_barrier(); } while (0)
#define ROT(v) (v) = ((v) == 2) ? 0 : (v) + 1

// ---- kernel 2: fused feature-gen + bf16 MFMA GEMM, split-K=4, trig-merged ----
// grid (32 row-tiles, 4 col-tiles, 4 k-chunks). 128 K-iters: 0..63 cos, 64..127 sin.
// B(n) in Bs[n%3], issued at n-2; A-fragments entirely in registers.
__global__ __launch_bounds__(256, 2) void fkan_gemm(const float4* __restrict__ csT2,
        const unsigned short* __restrict__ Wb, unsigned short* __restrict__ pb) {
    __shared__ unsigned short Bs[3][BN * 64];   // 3 x 16 KB ring (gl_lds dest)
    const int t = threadIdx.x;
    const int row0 = blockIdx.x * BM;
    const int col0 = blockIdx.y * BN;
    const int kz = blockIdx.z;
    const int k0 = kz * 4096;            // within-trig k offset
    const int i0 = kz * 128;             // starting input dim for this chunk
    const int l = t & 63, wv = t >> 6;
    const int wm = (wv & 1) * 64, wn = (wv >> 1) * 64;
    const int lm = l & 15, lq = l >> 4;
    const bool oddlq = (lq & 1) != 0;
    // gl_lds B staging: wave wv covers cols [col0+wv*32,+32), 4 instr x (8col x 128B)
    const int c8 = l & 7, s8 = l >> 3;
    const unsigned short* Bg0 = Wb + (size_t)(col0 + wv * 32 + c8) * KT + k0 + s8 * 8;
    // B-frag read base: seg(lq,h) = (lq>>1)*4 + (lq&1)*2 + h (matches A k-slices)
    const int bBase = ((wn >> 3) + (lm >> 3)) * 512
                    + ((lq >> 1) * 4 + (lq & 1) * 2) * 64 + (lm & 7) * 8;
    // per-tm seed base: csT2[(i0 + lq>>1)][row]; per-iter stride 2 dims = 8192
    const float4* sb[4];
    #pragma unroll
    for (int tm = 0; tm < 4; ++tm)
        sb[tm] = csT2 + (size_t)(i0 + (lq >> 1)) * N_ROWS
               + (row0 + wm + tm * 16 + lm);

    float4v acc[4][4];
    #pragma unroll
    for (int i = 0; i < 4; ++i)
        #pragma unroll
        for (int j = 0; j < 4; ++j)
            acc[i][j] = (float4v){0.f, 0.f, 0.f, 0.f};

    float4 sdA[4], sdB[4];
    // ---- prologue: B(0)->Bs[0], B(1)->Bs[1], seeds(0)->sdA. 12 VMEM in flight;
    // vmcnt(8) drains B(0). (B(1)+sdA drain at body(0)'s seed use.)
    #pragma unroll
    for (int j = 0; j < 4; ++j)
        gl_lds16(Bg0 + (size_t)(j * 8) * KT, &Bs[0][(wv * 4 + j) * 512]);
    #pragma unroll
    for (int j = 0; j < 4; ++j)
        gl_lds16(Bg0 + 64 + (size_t)(j * 8) * KT, &Bs[1][(wv * 4 + j) * 512]);
    #pragma unroll
    for (int tm = 0; tm < 4; ++tm)
        sdA[tm] = sb[tm][0];
    asm volatile("s_waitcnt vmcnt(8)" ::: "memory");
    __builtin_amdgcn_s_barrier();

    int rd = 0, wr = 2;
    #pragma unroll 1
    for (int it = 0; it < 64; it += 2) {   // cos half: bodies 0..63
        gemm_step<false, true, true>(it, rd, wr, Bs, Bg0, wv, sb, sdA, sdB,
                                     bBase, oddlq, acc);
        FENCE8(); ROT(rd); ROT(wr);
        gemm_step<false, true, true>(it + 1, rd, wr, Bs, Bg0, wv, sb, sdB, sdA,
                                     bBase, oddlq, acc);
        FENCE8(); ROT(rd); ROT(wr);
    }
    #pragma unroll 1
    for (int it = 64; it < 126; it += 2) { // sin half: bodies 64..125
        gemm_step<true, true, true>(it, rd, wr, Bs, Bg0, wv, sb, sdA, sdB,
                                    bBase, oddlq, acc);
        FENCE8(); ROT(rd); ROT(wr);
        gemm_step<true, true, true>(it + 1, rd, wr, Bs, Bg0, wv, sb, sdB, sdA,
                                    bBase, oddlq, acc);
        FENCE8(); ROT(rd); ROT(wr);
    }
    // body 126: no B prefetch; loads seeds(127); drain to seeds only + barrier
    gemm_step<true, false, true>(126, rd, wr, Bs, Bg0, wv, sb, sdA, sdB,
                                 bBase, oddlq, acc);
    asm volatile("s_waitcnt vmcnt(4)" ::: "memory");
    __builtin_amdgcn_s_barrier();
    ROT(rd);
    // body 127: pure compute
    gemm_step<true, false, false>(127, rd, wr, Bs, Bg0, wv, sb, sdB, sdA,
                                  bBase, oddlq, acc);

    // epilogue: C/D layout col=lane&15, row=quad*4+reg (m89-verified)
    unsigned short* pc = pb + (size_t)kz * N_ROWS * D_OUT;
    #pragma unroll
    for (int tm = 0; tm < 4; ++tm)
        #pragma unroll
        for (int tn = 0; tn < 4; ++tn)
            #pragma unroll
            for (int r = 0; r < 4; ++r) {
                const int row = row0 + wm + tm * 16 + lq * 4 + r;
                const int col = col0 + wn + tn * 16 + lm;
                pc[(size_t)row * D_OUT + col] = bf16_1(acc[tm][tn][r]);
            }
}

// ---- kernel 3: out = bias + sum of 4 bf16 partials (coalesced) ----
__global__ __launch_bounds__(256) void reduce_kernel(const unsigned short* __restrict__ pb,
        const float* __restrict__ bias, float* __restrict__ out) {
    const size_t e = ((size_t)blockIdx.x * 256 + threadIdx.x) * 4;
    const int col = (int)(e & (D_OUT - 1));
    float4 s = *(const float4*)(bias + col);
    #pragma unroll
    for (int c = 0; c < SPLITK; ++c) {
        ushort4 u = *(const ushort4*)(pb + (size_t)c * N_ROWS * D_OUT + e);
        union { unsigned int u; float f; } f0, f1, f2, f3;
        f0.u = (unsigned int)u.x << 16;
        f1.u = (unsigned int)u.y << 16;
        f2.u = (unsigned int)u.z << 16;
        f3.u = (unsigned int)u.w << 16;
        s.x += f0.f; s.y += f1.f; s.z += f2.f; s.w += f3.f;
    }
    *(float4*)(out + e) = s;
}

extern "C" void kernel_launch(void* const* d_in, const int* in_sizes, int n_in,
                              void* d_out, int out_size, void* d_ws, size_t ws_size,
                              hipStream_t stream) {
    const float* x    = (const float*)d_in[0];
    const float* ln_w = (const float*)d_in[1];
    const float* ln_b = (const float*)d_in[2];
    const float* fc   = (const float*)d_in[3];
    const float* bias = (const float*)d_in[4];
    float* out = (float*)d_out;

    float4* csT2 = (float4*)d_ws;                                       // 32 MB
    unsigned short* Wb = (unsigned short*)((char*)d_ws + (32u << 20));  // 32 MB
    unsigned short* pbp = (unsigned short*)((char*)d_ws + (64u << 20)); // 16 MB

    pre_kernel<<<256, 256, 0, stream>>>(x, ln_w, ln_b, fc, csT2, Wb);
    fkan_gemm<<<dim3(N_ROWS / BM, D_OUT / BN, SPLITK), 256, 0, stream>>>(csT2, Wb, pbp);
    reduce_kernel<<<2048, 256, 0, stream>>>(pbp, bias, out);            // 2.10M outs
}

// Round 4
// 295.354 us; speedup vs baseline: 1.1246x; 1.1246x over previous
//
#include <hip/hip_runtime.h>
#include <hip/hip_bf16.h>

// FourierKANLayer: N=4096, D_IN=512, D_OUT=512, G=32
// y = [cos/sin(k*LN(x)) features] @ W + bias  == GEMM M=4096,N=512,K=32768 (bf16 MFMA)
// R11: revert R10 (serial-chain + conflicts regression). R9 MFMA/VALU phase-
//      clumping fix via OCCUPANCY: LDS 48KB/block (single A buf + B dbuf,
//      depth-1 prefetch, vmcnt(1) counted fence) + SPLITK=8 (1024 blocks)
//      + __launch_bounds__(256,3) -> 3 blocks/CU = 12 waves/CU. Independent
//      blocks de-phase so MFMA of one hides staging VALU of another (m114).
// ws layout: [0,16MB)   csT float2[512][4096] = (cos xn, sin xn) seeds
//            [16MB,48MB) bf16 weights [2][512][16384] K-major (32 MiB)
//            [48MB,82MB) bf16 split-K partials [8][4096][512] (33.5 MiB)

#define N_ROWS 4096
#define D_IN   512
#define D_OUT  512
#define KT     16384   // per-trig K = D_IN*G
#define BM 128
#define BN 128
#define SPLITK 8
#define NT 64          // K-iters per block: 2 trig x 32 iters x 2 dims

typedef short short8 __attribute__((ext_vector_type(8)));
typedef float float4v __attribute__((ext_vector_type(4)));

__device__ inline unsigned int pack2bf(float a, float b) {
    __hip_bfloat162 h = __float22bfloat162_rn(make_float2(a, b));
    union { __hip_bfloat162 h; unsigned int u; } cv;
    cv.h = h;
    return cv.u;
}

__device__ inline unsigned short bf16_1(float a) {
    union { float f; unsigned int u; } cv;
    cv.f = a;
    unsigned int r = (cv.u + 0x7fff + ((cv.u >> 16) & 1)) >> 16;  // RN-even
    return (unsigned short)r;
}

// ---- kernel 1: fused LN stats + sincos seeds + W cast (one launch) ----
// 256 blocks x 256 thr; block owns 16 rows. Phase A: x tile -> LDS (pad 516),
// per-row stats via 16-lane shfl_xor. Phase B: normalize + __sincosf ->
// csT[dim][row] = {c1,s1} (16-row float2 bursts). Phase C: W fp32->bf16 cast.
__global__ __launch_bounds__(256) void pre_kernel(const float* __restrict__ x,
        const float* __restrict__ lnw, const float* __restrict__ lnb,
        const float* __restrict__ fc, float2* __restrict__ csT,
        unsigned short* __restrict__ Wb) {
    __shared__ __align__(16) float xs[16 * 516];
    __shared__ float2 murs[16];
    const int t = threadIdx.x;
    const int r0 = blockIdx.x * 16;
    {
        const int row = t >> 4, tq = t & 15;
        const float* xr = x + (size_t)(r0 + row) * D_IN;
        float s = 0.f, q = 0.f;
        #pragma unroll
        for (int k = 0; k < 8; ++k) {
            float4 v = *(const float4*)(xr + tq * 4 + k * 64);
            *(float4*)&xs[row * 516 + tq * 4 + k * 64] = v;
            s += v.x + v.y + v.z + v.w;
            q += v.x * v.x + v.y * v.y + v.z * v.z + v.w * v.w;
        }
        #pragma unroll
        for (int off = 8; off > 0; off >>= 1) {
            s += __shfl_xor(s, off, 16);
            q += __shfl_xor(q, off, 16);
        }
        if (tq == 0) {
            float mu = s * (1.f / D_IN);
            float var = q * (1.f / D_IN) - mu * mu;
            murs[row] = make_float2(mu, rsqrtf(var + 1e-5f));
        }
    }
    __syncthreads();
    {
        const int brow = t & 15, dimg = t >> 4;
        const float2 mr = murs[brow];
        #pragma unroll 4
        for (int j = 0; j < 32; ++j) {
            const int dim = j * 16 + dimg;
            float xv = xs[brow * 516 + dim];
            float xn = (xv - mr.x) * mr.y * lnw[dim] + lnb[dim];
            float s1, c1;
            __sincosf(xn, &s1, &c1);
            csT[(size_t)dim * N_ROWS + r0 + brow] = make_float2(c1, s1);
        }
    }
    {   // W cast: 16.78M floats = 256 blk x 256 thr x 8 x 32
        size_t e = ((size_t)blockIdx.x * 256 + t) * 8;
        for (int it2 = 0; it2 < 32; ++it2, e += (size_t)256 * 256 * 8) {
            const float4* in = (const float4*)(fc + e);
            float4 a = in[0], c = in[1];
            uint4 o;
            o.x = pack2bf(a.x, a.y);
            o.y = pack2bf(a.z, a.w);
            o.z = pack2bf(c.x, c.y);
            o.w = pack2bf(c.z, c.w);
            *(uint4*)(Wb + e) = o;
        }
    }
}

// ---- feature staging: Chebyshev chain -> swizzled A LDS tile ----
// A layout: [row][64 shorts], 16B chunk kc stored at chunk index kc^(row&7).
// 128 threads-pairs: thread (frow, ihalf) computes 32 harmonics of one dim.
__device__ inline void stage_feats(unsigned short* Abuf, float2 cs, int ttype,
                                   int frow, int ihalf) {
    const float c1 = cs.x, s1 = cs.y;
    const float c2 = c1 + c1;
    float prev = ttype ? 0.f : 1.f;
    float cur  = ttype ? s1 : c1;
    const int rbase = frow * 64;
    const int sw = frow & 7;
    unsigned int us[4];
    #pragma unroll
    for (int d = 0; d < 16; ++d) {
        float f0 = cur;
        float f1 = __builtin_fmaf(c2, cur, -prev);
        float f2 = __builtin_fmaf(c2, f1, -cur);
        prev = f1;
        cur = f2;
        us[d & 3] = pack2bf(f0, f1);
        if ((d & 3) == 3) {
            const int kc = ihalf * 4 + (d >> 2);
            *(uint4*)&Abuf[rbase + ((kc ^ sw) << 3)] =
                make_uint4(us[0], us[1], us[2], us[3]);
        }
    }
}

__device__ inline void gl_lds16(const unsigned short* gsrc, unsigned short* ldst) {
    __builtin_amdgcn_global_load_lds(
        (const __attribute__((address_space(1))) unsigned int*)gsrc,
        (__attribute__((address_space(3))) unsigned int*)ldst, 16, 0, 0);
}

__device__ inline void read_af(const unsigned short* As, short8 (&af)[2][4],
                               int wm, int lm, int lq, int swA) {
    #pragma unroll
    for (int h = 0; h < 2; ++h)
        #pragma unroll
        for (int tm = 0; tm < 4; ++tm)
            af[h][tm] = *(const short8*)
                &As[(wm + tm * 16 + lm) * 64 + (((h * 4 + lq) ^ swA) << 3)];
}

__device__ inline void read_bf(const unsigned short* Bp, short8 (&bf)[2][4],
                               int bBase) {
    #pragma unroll
    for (int h = 0; h < 2; ++h)
        #pragma unroll
        for (int tn = 0; tn < 4; ++tn)
            bf[h][tn] = *(const short8*)&Bp[bBase + tn * 1024 + h * 256];
}

__device__ inline void mfma_block(short8 (&af)[2][4], short8 (&bf)[2][4],
                                  float4v (&acc)[4][4]) {
    __builtin_amdgcn_s_setprio(1);
    #pragma unroll
    for (int h = 0; h < 2; ++h)
        #pragma unroll
        for (int tm = 0; tm < 4; ++tm)
            #pragma unroll
            for (int tn = 0; tn < 4; ++tn)
                acc[tm][tn] = __builtin_amdgcn_mfma_f32_16x16x32_bf16(
                    af[h][tm], bf[h][tn], acc[tm][tn], 0, 0, 0);
    __builtin_amdgcn_s_setprio(0);
}

// ---- kernel 2: fused feature-gen + bf16 MFMA GEMM, split-K=8, trig-merged ----
// grid (32 row-tiles, 4 col-tiles, 8 k-chunks) = 1024 blocks -> 3/CU resident.
// NT=64 K-iters: 0..31 cos, 32..63 sin (2 dims x 32 harmonics per iter).
// B(n) in Bs[n&1], issued at n-1 (fence vmcnt(1): gl_lds drained, seed left
// in flight; order pinned by sched_barrier). A single-buffered: af register-
// read pre-barrier, restaged post-barrier (R8-proven pattern).
__global__ __launch_bounds__(256, 3) void fkan_gemm(const float2* __restrict__ csT,
        const unsigned short* __restrict__ Wb, unsigned short* __restrict__ pb) {
    __shared__ unsigned short As[BM * 64];      // 16 KB, swizzled
    __shared__ unsigned short Bs[2][BN * 64];   // 2 x 16 KB (gl_lds dest)
    const int t = threadIdx.x;
    const int row0 = blockIdx.x * BM;
    const int col0 = blockIdx.y * BN;
    const int kz = blockIdx.z;
    const int k0 = kz * 2048;            // within-trig k offset (64 dims * 32)
    const int i0 = kz * 64;              // starting input dim for this chunk
    const int frow = t & 127;            // A-staging row
    const int ihalf = t >> 7;            // which of the 2 dims per iter
    const int l = t & 63, wv = t >> 6;
    const int wm = (wv & 1) * 64, wn = (wv >> 1) * 64;
    const int lm = l & 15, lq = l >> 4;
    // gl_lds B staging: wave wv covers cols [col0+wv*32,+32), 4 instr x (8col x 128B)
    const int c8 = l & 7, s8 = l >> 3;
    const unsigned short* Bg0 = Wb + (size_t)(col0 + wv * 32 + c8) * KT + k0 + s8 * 8;
    const int swA = lm & 7;
    // B-frag read base (shorts): gi*512 + lq*64 + ci*8  (R9 layout, 0-conflict)
    const int bBase = ((wn >> 3) + (lm >> 3)) * 512 + lq * 64 + (lm & 7) * 8;

    const float2* csBase = csT + (size_t)(i0 + ihalf) * N_ROWS + row0 + frow;

    float4v acc[4][4];
    #pragma unroll
    for (int i = 0; i < 4; ++i)
        #pragma unroll
        for (int j = 0; j < 4; ++j)
            acc[i][j] = (float4v){0.f, 0.f, 0.f, 0.f};

    // ---- prologue: seed(0), B(0)->Bs[0], seed(1), stage A(0).
    float2 cs0 = csBase[0];
    #pragma unroll
    for (int j = 0; j < 4; ++j)
        gl_lds16(Bg0 + (size_t)(j * 8) * KT, &Bs[0][(wv * 4 + j) * 512]);
    __builtin_amdgcn_sched_barrier(0);           // pin: gl_lds before seed load
    float2 csA = csBase[2 * N_ROWS];             // seed for A(1)
    stage_feats(As, cs0, 0, frow, ihalf);
    asm volatile("s_waitcnt vmcnt(1) lgkmcnt(0)" ::: "memory");  // B(0) landed
    __builtin_amdgcn_s_barrier();

    // ---- main loop: iters 0..62
    #pragma unroll 1
    for (int it = 0; it < NT - 1; ++it) {
        const int p = it & 1;
        // A(it) fragments -> regs (As restaged after barrier #1)
        short8 af[2][4];
        read_af(As, af, wm, lm, lq, swA);
        // issue B(it+1) -> Bs[p^1]
        {
            const int n = it + 1;
            const unsigned short* gb =
                Bg0 + (size_t)(n >> 5) * D_OUT * KT + (n & 31) * 64;
            unsigned short* ldst = &Bs[p ^ 1][(wv * 4) * 512];
            #pragma unroll
            for (int j = 0; j < 4; ++j)
                gl_lds16(gb + (size_t)(j * 8) * KT, ldst + j * 512);
        }
        __builtin_amdgcn_sched_barrier(0);       // pin: gl_lds before seed load
        float2 csN = csBase[(size_t)(((it + 2) & 31) * 2) * N_ROWS]; // seeds(it+2)
        asm volatile("s_waitcnt lgkmcnt(0)" ::: "memory");   // my af reads done
        __builtin_amdgcn_s_barrier();            // all af reads done -> As free
        // stage A(it+1) (VALU+LDS-write) || B(it) frag reads || MFMA
        stage_feats(As, csA, (it + 1) >> 5, frow, ihalf);
        csA = csN;
        short8 bf[2][4];
        read_bf(&Bs[p][0], bf, bBase);
        mfma_block(af, bf, acc);
        // B(it+1)'s 4 gl_lds drained (seed stays in flight); A(it+1) published.
        asm volatile("s_waitcnt vmcnt(1) lgkmcnt(0)" ::: "memory");
        __builtin_amdgcn_s_barrier();
    }
    // ---- iter 63: pure compute (A(63) and B(63) both published)
    {
        short8 af[2][4];
        read_af(As, af, wm, lm, lq, swA);
        short8 bf[2][4];
        read_bf(&Bs[1][0], bf, bBase);   // 63 & 1 == 1
        mfma_block(af, bf, acc);
    }
    // epilogue: C/D layout col=lane&15, row=quad*4+reg (m89-verified)
    unsigned short* pc = pb + (size_t)kz * N_ROWS * D_OUT;
    #pragma unroll
    for (int tm = 0; tm < 4; ++tm)
        #pragma unroll
        for (int tn = 0; tn < 4; ++tn)
            #pragma unroll
            for (int r = 0; r < 4; ++r) {
                const int row = row0 + wm + tm * 16 + lq * 4 + r;
                const int col = col0 + wn + tn * 16 + lm;
                pc[(size_t)row * D_OUT + col] = bf16_1(acc[tm][tn][r]);
            }
}

// ---- kernel 3: out = bias + sum of 8 bf16 partials (coalesced) ----
__global__ __launch_bounds__(256) void reduce_kernel(const unsigned short* __restrict__ pb,
        const float* __restrict__ bias, float* __restrict__ out) {
    const size_t e = ((size_t)blockIdx.x * 256 + threadIdx.x) * 4;
    const int col = (int)(e & (D_OUT - 1));
    float4 s = *(const float4*)(bias + col);
    #pragma unroll
    for (int c = 0; c < SPLITK; ++c) {
        ushort4 u = *(const ushort4*)(pb + (size_t)c * N_ROWS * D_OUT + e);
        union { unsigned int u; float f; } f0, f1, f2, f3;
        f0.u = (unsigned int)u.x << 16;
        f1.u = (unsigned int)u.y << 16;
        f2.u = (unsigned int)u.z << 16;
        f3.u = (unsigned int)u.w << 16;
        s.x += f0.f; s.y += f1.f; s.z += f2.f; s.w += f3.f;
    }
    *(float4*)(out + e) = s;
}

extern "C" void kernel_launch(void* const* d_in, const int* in_sizes, int n_in,
                              void* d_out, int out_size, void* d_ws, size_t ws_size,
                              hipStream_t stream) {
    const float* x    = (const float*)d_in[0];
    const float* ln_w = (const float*)d_in[1];
    const float* ln_b = (const float*)d_in[2];
    const float* fc   = (const float*)d_in[3];
    const float* bias = (const float*)d_in[4];
    float* out = (float*)d_out;

    float2* csT = (float2*)d_ws;                                        // 16 MB
    unsigned short* Wb = (unsigned short*)((char*)d_ws + (16u << 20));  // 32 MB
    unsigned short* pbp = (unsigned short*)((char*)d_ws + (48u << 20)); // 33.5 MB

    pre_kernel<<<256, 256, 0, stream>>>(x, ln_w, ln_b, fc, csT, Wb);
    fkan_gemm<<<dim3(N_ROWS / BM, D_OUT / BN, SPLITK), 256, 0, stream>>>(csT, Wb, pbp);
    reduce_kernel<<<2048, 256, 0, stream>>>(pbp, bias, out);            // 2.10M outs
}

// Round 6
// 265.534 us; speedup vs baseline: 1.2509x; 1.1123x over previous
//
#include <hip/hip_runtime.h>
#include <hip/hip_bf16.h>

// FourierKANLayer: N=4096, D_IN=512, D_OUT=512, G=32
// y = [cos/sin(k*LN(x)) features] @ W + bias  == GEMM M=4096,N=512,K=32768 (bf16 MFMA)
// R12b: producer/consumer wave specialization (R12) + hardened fences.
//      512-thr blocks: waves 0-3 pure MFMA consumers, waves 4-7 producers
//      (B gl_lds DMA + seed loads + Chebyshev A-staging, counted vmcnt(1)).
//      A,B double-buffered: ONE barrier/iter, 64KB LDS -> 2 blocks/CU.
//      Consumer barriers now carry lgkmcnt(0)+"memory" fences: LLVM's
//      s_barrier is IntrNoMem, so without the clobber the scheduler may
//      hoist next-iter ds_reads above the barrier (race vs A-restage).
// ws layout: [0,16MB)   csT float2[512][4096] = (cos xn, sin xn) seeds
//            [16MB,48MB) bf16 weights [2][512][16384] K-major (32 MiB)
//            [48MB,64MB) bf16 split-K partials [4][4096][512] (16 MiB)

#define N_ROWS 4096
#define D_IN   512
#define D_OUT  512
#define KT     16384   // per-trig K = D_IN*G
#define BM 128
#define BN 128
#define SPLITK 4
#define NT 128         // K-iters per block: 2 trig x 64 (2 dims x 32 harmonics)

typedef short short8 __attribute__((ext_vector_type(8)));
typedef float float4v __attribute__((ext_vector_type(4)));

__device__ inline unsigned int pack2bf(float a, float b) {
    __hip_bfloat162 h = __float22bfloat162_rn(make_float2(a, b));
    union { __hip_bfloat162 h; unsigned int u; } cv;
    cv.h = h;
    return cv.u;
}

__device__ inline unsigned short bf16_1(float a) {
    union { float f; unsigned int u; } cv;
    cv.f = a;
    unsigned int r = (cv.u + 0x7fff + ((cv.u >> 16) & 1)) >> 16;  // RN-even
    return (unsigned short)r;
}

// ---- kernel 1: fused LN stats + sincos seeds + W cast (one launch) ----
__global__ __launch_bounds__(256) void pre_kernel(const float* __restrict__ x,
        const float* __restrict__ lnw, const float* __restrict__ lnb,
        const float* __restrict__ fc, float2* __restrict__ csT,
        unsigned short* __restrict__ Wb) {
    __shared__ __align__(16) float xs[16 * 516];
    __shared__ float2 murs[16];
    const int t = threadIdx.x;
    const int r0 = blockIdx.x * 16;
    {
        const int row = t >> 4, tq = t & 15;
        const float* xr = x + (size_t)(r0 + row) * D_IN;
        float s = 0.f, q = 0.f;
        #pragma unroll
        for (int k = 0; k < 8; ++k) {
            float4 v = *(const float4*)(xr + tq * 4 + k * 64);
            *(float4*)&xs[row * 516 + tq * 4 + k * 64] = v;
            s += v.x + v.y + v.z + v.w;
            q += v.x * v.x + v.y * v.y + v.z * v.z + v.w * v.w;
        }
        #pragma unroll
        for (int off = 8; off > 0; off >>= 1) {
            s += __shfl_xor(s, off, 16);
            q += __shfl_xor(q, off, 16);
        }
        if (tq == 0) {
            float mu = s * (1.f / D_IN);
            float var = q * (1.f / D_IN) - mu * mu;
            murs[row] = make_float2(mu, rsqrtf(var + 1e-5f));
        }
    }
    __syncthreads();
    {
        const int brow = t & 15, dimg = t >> 4;
        const float2 mr = murs[brow];
        #pragma unroll 4
        for (int j = 0; j < 32; ++j) {
            const int dim = j * 16 + dimg;
            float xv = xs[brow * 516 + dim];
            float xn = (xv - mr.x) * mr.y * lnw[dim] + lnb[dim];
            float s1, c1;
            __sincosf(xn, &s1, &c1);
            csT[(size_t)dim * N_ROWS + r0 + brow] = make_float2(c1, s1);
        }
    }
    {   // W cast: 16.78M floats = 256 blk x 256 thr x 8 x 32
        size_t e = ((size_t)blockIdx.x * 256 + t) * 8;
        for (int it2 = 0; it2 < 32; ++it2, e += (size_t)256 * 256 * 8) {
            const float4* in = (const float4*)(fc + e);
            float4 a = in[0], c = in[1];
            uint4 o;
            o.x = pack2bf(a.x, a.y);
            o.y = pack2bf(a.z, a.w);
            o.z = pack2bf(c.x, c.y);
            o.w = pack2bf(c.z, c.w);
            *(uint4*)(Wb + e) = o;
        }
    }
}

// ---- feature staging: Chebyshev chain -> swizzled A LDS tile ----
// A layout: [row][64 shorts], 16B chunk kc stored at chunk index kc^(row&7).
__device__ inline void stage_feats(unsigned short* Abuf, float2 cs, int ttype,
                                   int frow, int ihalf) {
    const float c1 = cs.x, s1 = cs.y;
    const float c2 = c1 + c1;
    float prev = ttype ? 0.f : 1.f;
    float cur  = ttype ? s1 : c1;
    const int rbase = frow * 64;
    const int sw = frow & 7;
    unsigned int us[4];
    #pragma unroll
    for (int d = 0; d < 16; ++d) {
        float f0 = cur;
        float f1 = __builtin_fmaf(c2, cur, -prev);
        float f2 = __builtin_fmaf(c2, f1, -cur);
        prev = f1;
        cur = f2;
        us[d & 3] = pack2bf(f0, f1);
        if ((d & 3) == 3) {
            const int kc = ihalf * 4 + (d >> 2);
            *(uint4*)&Abuf[rbase + ((kc ^ sw) << 3)] =
                make_uint4(us[0], us[1], us[2], us[3]);
        }
    }
}

__device__ inline void gl_lds16(const unsigned short* gsrc, unsigned short* ldst) {
    __builtin_amdgcn_global_load_lds(
        (const __attribute__((address_space(1))) unsigned int*)gsrc,
        (__attribute__((address_space(3))) unsigned int*)ldst, 16, 0, 0);
}

// ---- kernel 2: fused feature-gen + bf16 MFMA GEMM, split-K=4, trig-merged ----
// grid (32 row-tiles, 4 col-tiles, 4 kz) = 512 blocks x 512 thr -> 2 blocks/CU.
// NT=128 K-iters: 0..63 cos, 64..127 sin (2 dims x 32 harmonics per iter).
// Consumers (t<256): read af/bf from published [it&1] buffers, 32 MFMA,
//   lgkmcnt(0)+fence, barrier. Producers (t>=256): DMA B(it+1)->Bs[(it+1)&1],
//   seed(it+2), stage A(it+1)->As[(it+1)&1], vmcnt(1) lgkmcnt(0), barrier.
// Barrier counts match: 128 each path.
__global__ __launch_bounds__(512, 4) void fkan_gemm(const float2* __restrict__ csT,
        const unsigned short* __restrict__ Wb, unsigned short* __restrict__ pb) {
    __shared__ unsigned short As[2][BM * 64];   // 2 x 16 KB, swizzled
    __shared__ unsigned short Bs[2][BN * 64];   // 2 x 16 KB (gl_lds dest)
    const int t = threadIdx.x;
    const int row0 = blockIdx.x * BM;
    const int col0 = blockIdx.y * BN;
    const int kz = blockIdx.z;
    const int k0 = kz * 4096;            // within-trig k offset
    const int i0 = kz * 128;             // starting input dim for this chunk

    if (t < 256) {
        // ================= CONSUMER: pure MFMA =================
        const int l = t & 63, wv = t >> 6;
        const int wm = (wv & 1) * 64, wn = (wv >> 1) * 64;
        const int lm = l & 15, lq = l >> 4;
        const int swA = lm & 7;
        // B-frag read base (shorts): gi*512 + lq*64 + ci*8 (0-conflict layout)
        const int bBase = ((wn >> 3) + (lm >> 3)) * 512 + lq * 64 + (lm & 7) * 8;

        float4v acc[4][4];
        #pragma unroll
        for (int i = 0; i < 4; ++i)
            #pragma unroll
            for (int j = 0; j < 4; ++j)
                acc[i][j] = (float4v){0.f, 0.f, 0.f, 0.f};

        __builtin_amdgcn_s_barrier();            // wait A(0), B(0)
        asm volatile("" ::: "memory");           // no reads hoist above barrier
        #pragma unroll 1
        for (int it = 0; it < NT; ++it) {
            const unsigned short* Ap = &As[it & 1][0];
            const unsigned short* Bp = &Bs[it & 1][0];
            __builtin_amdgcn_s_setprio(1);
            #pragma unroll
            for (int h = 0; h < 2; ++h) {
                short8 af[4], bf[4];
                #pragma unroll
                for (int tm = 0; tm < 4; ++tm)
                    af[tm] = *(const short8*)
                        &Ap[(wm + tm * 16 + lm) * 64 + (((h * 4 + lq) ^ swA) << 3)];
                #pragma unroll
                for (int tn = 0; tn < 4; ++tn)
                    bf[tn] = *(const short8*)&Bp[bBase + tn * 1024 + h * 256];
                #pragma unroll
                for (int tm = 0; tm < 4; ++tm)
                    #pragma unroll
                    for (int tn = 0; tn < 4; ++tn)
                        acc[tm][tn] = __builtin_amdgcn_mfma_f32_16x16x32_bf16(
                            af[tm], bf[tn], acc[tm][tn], 0, 0, 0);
            }
            __builtin_amdgcn_s_setprio(0);
            if (it < NT - 1) {
                // my LDS reads fully drained BEFORE licensing buffer overwrite;
                // "memory" clobber pins reads/MFMAs on the correct barrier side
                asm volatile("s_waitcnt lgkmcnt(0)" ::: "memory");
                __builtin_amdgcn_s_barrier();
                asm volatile("" ::: "memory");
            }
        }
        // epilogue: C/D layout col=lane&15, row=quad*4+reg (m89-verified)
        unsigned short* pc = pb + (size_t)kz * N_ROWS * D_OUT;
        #pragma unroll
        for (int tm = 0; tm < 4; ++tm)
            #pragma unroll
            for (int tn = 0; tn < 4; ++tn)
                #pragma unroll
                for (int r = 0; r < 4; ++r) {
                    const int row = row0 + wm + tm * 16 + lq * 4 + r;
                    const int col = col0 + wn + tn * 16 + lm;
                    pc[(size_t)row * D_OUT + col] = bf16_1(acc[tm][tn][r]);
                }
    } else {
        // ================= PRODUCER: staging only =================
        const int u = t - 256;
        const int frow = u & 127;            // A-staging row
        const int ihalf = u >> 7;            // which of the 2 dims per iter
        const int pl = u & 63, pw = u >> 6;  // producer lane / wave
        // gl_lds B staging: producer wave pw covers cols [col0+pw*32, +32)
        const int c8 = pl & 7, s8 = pl >> 3;
        const unsigned short* Bg0 =
            Wb + (size_t)(col0 + pw * 32 + c8) * KT + k0 + s8 * 8;
        const float2* csBase = csT + (size_t)(i0 + ihalf) * N_ROWS + row0 + frow;

        // prologue: seed(0) -> stage A(0); DMA B(0); seed(1) kept in flight
        float2 cs0 = csBase[0];
        #pragma unroll
        for (int j = 0; j < 4; ++j)
            gl_lds16(Bg0 + (size_t)(j * 8) * KT, &Bs[0][(pw * 4 + j) * 512]);
        __builtin_amdgcn_sched_barrier(0);       // pin: gl_lds before seed load
        float2 csA = csBase[2 * N_ROWS];         // seed for A(1)
        stage_feats(&As[0][0], cs0, 0, frow, ihalf);
        asm volatile("s_waitcnt vmcnt(1) lgkmcnt(0)" ::: "memory");
        __builtin_amdgcn_s_barrier();            // publish A(0), B(0)
        asm volatile("" ::: "memory");

        #pragma unroll 1
        for (int it = 0; it < NT - 1; ++it) {
            const int n = it + 1;
            // DMA B(n) -> Bs[n&1]
            const unsigned short* gb =
                Bg0 + (size_t)(n >> 6) * D_OUT * KT + (n & 63) * 64;
            unsigned short* ldst = &Bs[n & 1][(pw * 4) * 512];
            #pragma unroll
            for (int j = 0; j < 4; ++j)
                gl_lds16(gb + (size_t)(j * 8) * KT, ldst + j * 512);
            __builtin_amdgcn_sched_barrier(0);   // pin: gl_lds before seed load
            float2 csN = csBase[(size_t)(((it + 2) & 63) * 2) * N_ROWS];
            // stage A(n) -> As[n&1] (consumer reads As[it&1] concurrently)
            stage_feats(&As[n & 1][0], csA, n >> 6, frow, ihalf);
            csA = csN;
            // 4 gl_lds drained; seed(it+2) stays in flight (never vmcnt 0)
            asm volatile("s_waitcnt vmcnt(1) lgkmcnt(0)" ::: "memory");
            __builtin_amdgcn_s_barrier();        // publish A(n), B(n)
            asm volatile("" ::: "memory");
        }
        // producers done: no more barriers on either path
    }
}

// ---- kernel 3: out = bias + sum of 4 bf16 partials (coalesced) ----
__global__ __launch_bounds__(256) void reduce_kernel(const unsigned short* __restrict__ pb,
        const float* __restrict__ bias, float* __restrict__ out) {
    const size_t e = ((size_t)blockIdx.x * 256 + threadIdx.x) * 4;
    const int col = (int)(e & (D_OUT - 1));
    float4 s = *(const float4*)(bias + col);
    #pragma unroll
    for (int c = 0; c < SPLITK; ++c) {
        ushort4 u = *(const ushort4*)(pb + (size_t)c * N_ROWS * D_OUT + e);
        union { unsigned int u; float f; } f0, f1, f2, f3;
        f0.u = (unsigned int)u.x << 16;
        f1.u = (unsigned int)u.y << 16;
        f2.u = (unsigned int)u.z << 16;
        f3.u = (unsigned int)u.w << 16;
        s.x += f0.f; s.y += f1.f; s.z += f2.f; s.w += f3.f;
    }
    *(float4*)(out + e) = s;
}

extern "C" void kernel_launch(void* const* d_in, const int* in_sizes, int n_in,
                              void* d_out, int out_size, void* d_ws, size_t ws_size,
                              hipStream_t stream) {
    const float* x    = (const float*)d_in[0];
    const float* ln_w = (const float*)d_in[1];
    const float* ln_b = (const float*)d_in[2];
    const float* fc   = (const float*)d_in[3];
    const float* bias = (const float*)d_in[4];
    float* out = (float*)d_out;

    float2* csT = (float2*)d_ws;                                        // 16 MB
    unsigned short* Wb = (unsigned short*)((char*)d_ws + (16u << 20));  // 32 MB
    unsigned short* pbp = (unsigned short*)((char*)d_ws + (48u << 20)); // 16 MB

    pre_kernel<<<256, 256, 0, stream>>>(x, ln_w, ln_b, fc, csT, Wb);
    fkan_gemm<<<dim3(N_ROWS / BM, D_OUT / BN, SPLITK), 512, 0, stream>>>(csT, Wb, pbp);
    reduce_kernel<<<2048, 256, 0, stream>>>(pbp, bias, out);            // 2.10M outs
}

// Round 7
// 253.557 us; speedup vs baseline: 1.3100x; 1.0472x over previous
//
#include <hip/hip_runtime.h>
#include <hip/hip_bf16.h>

// FourierKANLayer: N=4096, D_IN=512, D_OUT=512, G=32
// y = [cos/sin(k*LN(x)) features] @ W + bias  == GEMM M=4096,N=512,K=32768 (bf16 MFMA)
// R13: m201 8-phase 256^2 port (T2/T3/T4/T5 stack), generated-A variant.
//      BM=BN=256, BK=64, 512 thr, 8 waves (2Mx4N), wave-tile 128x64,
//      acc[8][4] (128/lane). LDS 128KB: A dbuf 2x32KB (XOR-swizzled,
//      Chebyshev-staged in 4 phase-quarters) + B dbuf 2x32KB (gl_lds).
//      Per K-tile 4 phases x {reads+stage; barrier; lgkmcnt(0); 16 MFMA;
//      barrier}; vmcnt(1) ONLY at phase 3 (loads span phases — T4).
//      SPLITK=8, grid 16x2x8 = 256 blocks = 1/CU.
// ws layout: [0,16MB)   csT float2[512][4096] = (cos xn, sin xn) seeds
//            [16MB,48MB) bf16 weights [2][512][16384] K-major (32 MiB)
//            [48MB,80MB) bf16 split-K partials [8][4096][512] (32 MiB)

#define N_ROWS 4096
#define D_IN   512
#define D_OUT  512
#define KT     16384   // per-trig K = D_IN*G
#define BM 256
#define BN 256
#define SPLITK 8
#define NT 64          // K-tiles per block: 2 trig x 32 dim-pairs (BK=64)

typedef short short8 __attribute__((ext_vector_type(8)));
typedef float float4v __attribute__((ext_vector_type(4)));

__device__ inline unsigned int pack2bf(float a, float b) {
    __hip_bfloat162 h = __float22bfloat162_rn(make_float2(a, b));
    union { __hip_bfloat162 h; unsigned int u; } cv;
    cv.h = h;
    return cv.u;
}

__device__ inline unsigned short bf16_1(float a) {
    union { float f; unsigned int u; } cv;
    cv.f = a;
    unsigned int r = (cv.u + 0x7fff + ((cv.u >> 16) & 1)) >> 16;  // RN-even
    return (unsigned short)r;
}

// ---- kernel 1: fused LN stats + sincos seeds + W cast (one launch) ----
__global__ __launch_bounds__(256) void pre_kernel(const float* __restrict__ x,
        const float* __restrict__ lnw, const float* __restrict__ lnb,
        const float* __restrict__ fc, float2* __restrict__ csT,
        unsigned short* __restrict__ Wb) {
    __shared__ __align__(16) float xs[16 * 516];
    __shared__ float2 murs[16];
    const int t = threadIdx.x;
    const int r0 = blockIdx.x * 16;
    {
        const int row = t >> 4, tq = t & 15;
        const float* xr = x + (size_t)(r0 + row) * D_IN;
        float s = 0.f, q = 0.f;
        #pragma unroll
        for (int k = 0; k < 8; ++k) {
            float4 v = *(const float4*)(xr + tq * 4 + k * 64);
            *(float4*)&xs[row * 516 + tq * 4 + k * 64] = v;
            s += v.x + v.y + v.z + v.w;
            q += v.x * v.x + v.y * v.y + v.z * v.z + v.w * v.w;
        }
        #pragma unroll
        for (int off = 8; off > 0; off >>= 1) {
            s += __shfl_xor(s, off, 16);
            q += __shfl_xor(q, off, 16);
        }
        if (tq == 0) {
            float mu = s * (1.f / D_IN);
            float var = q * (1.f / D_IN) - mu * mu;
            murs[row] = make_float2(mu, rsqrtf(var + 1e-5f));
        }
    }
    __syncthreads();
    {
        const int brow = t & 15, dimg = t >> 4;
        const float2 mr = murs[brow];
        #pragma unroll 4
        for (int j = 0; j < 32; ++j) {
            const int dim = j * 16 + dimg;
            float xv = xs[brow * 516 + dim];
            float xn = (xv - mr.x) * mr.y * lnw[dim] + lnb[dim];
            float s1, c1;
            __sincosf(xn, &s1, &c1);
            csT[(size_t)dim * N_ROWS + r0 + brow] = make_float2(c1, s1);
        }
    }
    {   // W cast: 16.78M floats = 256 blk x 256 thr x 8 x 32
        size_t e = ((size_t)blockIdx.x * 256 + t) * 8;
        for (int it2 = 0; it2 < 32; ++it2, e += (size_t)256 * 256 * 8) {
            const float4* in = (const float4*)(fc + e);
            float4 a = in[0], c = in[1];
            uint4 o;
            o.x = pack2bf(a.x, a.y);
            o.y = pack2bf(a.z, a.w);
            o.z = pack2bf(c.x, c.y);
            o.w = pack2bf(c.z, c.w);
            *(uint4*)(Wb + e) = o;
        }
    }
}

// ---- feature staging (full tile, prologue only): Chebyshev -> swizzled A ----
// A layout: [row][64 shorts], 16B chunk kc stored at chunk index kc^(row&7).
__device__ inline void stage_feats(unsigned short* Abuf, float2 cs, int ttype,
                                   int frow, int ihalf) {
    const float c1 = cs.x, s1 = cs.y;
    const float c2 = c1 + c1;
    float prev = ttype ? 0.f : 1.f;
    float cur  = ttype ? s1 : c1;
    const int rbase = frow * 64;
    const int sw = frow & 7;
    unsigned int us[4];
    #pragma unroll
    for (int d = 0; d < 16; ++d) {
        float f0 = cur;
        float f1 = __builtin_fmaf(c2, cur, -prev);
        float f2 = __builtin_fmaf(c2, f1, -cur);
        prev = f1;
        cur = f2;
        us[d & 3] = pack2bf(f0, f1);
        if ((d & 3) == 3) {
            const int kc = ihalf * 4 + (d >> 2);
            *(uint4*)&Abuf[rbase + ((kc ^ sw) << 3)] =
                make_uint4(us[0], us[1], us[2], us[3]);
        }
    }
}

__device__ inline void gl_lds16(const unsigned short* gsrc, unsigned short* ldst) {
    __builtin_amdgcn_global_load_lds(
        (const __attribute__((address_space(1))) unsigned int*)gsrc,
        (__attribute__((address_space(3))) unsigned int*)ldst, 16, 0, 0);
}

// ---- one K-tile: 4 phases, m201 template. PF=false for the last tile. ----
template<bool PF>
__device__ __forceinline__ void gemm_tile(int tt,
        const unsigned short* Ap, const unsigned short* Bp,
        unsigned short* Aw, unsigned short* Bw,
        const unsigned short* Bg0, const float2* csBase, float2& csA,
        int wv, int wrow, int lm, int lq, int swA, int bBase,
        int arow, int adim, float4v (&acc)[8][4]) {
    // Chebyshev chain state for A(tt+1), advanced 8 harmonics per phase
    const int ttype1 = ((tt + 1) >> 5) & 1;
    const float c2 = csA.x + csA.x;
    float prev = ttype1 ? 0.f : 1.f;
    float cur  = ttype1 ? csA.y : csA.x;
    float2 csN = csA;
    short8 bf[2][4];
    #pragma unroll
    for (int p = 0; p < 4; ++p) {
        // af for this phase: m-frags 2p, 2p+1
        short8 af[2][2];
        #pragma unroll
        for (int h = 0; h < 2; ++h)
            #pragma unroll
            for (int j = 0; j < 2; ++j)
                af[h][j] = *(const short8*)
                    &Ap[(wrow * 128 + (2 * p + j) * 16 + lm) * 64
                        + (((h * 4 + lq) ^ swA) << 3)];
        if (p == 0) {
            #pragma unroll
            for (int h = 0; h < 2; ++h)
                #pragma unroll
                for (int n = 0; n < 4; ++n)
                    bf[h][n] = *(const short8*)&Bp[bBase + n * 1024 + h * 256];
            if (PF) {   // all 4 B(tt+1) loads issued HERE: span 4 phases (T4)
                const int n1 = tt + 1;
                const unsigned short* gb =
                    Bg0 + (size_t)(n1 >> 5) * D_OUT * KT + (n1 & 31) * 64;
                unsigned short* ldst = Bw + (wv * 4) * 512;
                #pragma unroll
                for (int j2 = 0; j2 < 4; ++j2)
                    gl_lds16(gb + (size_t)(j2 * 8) * KT, ldst + j2 * 512);
                __builtin_amdgcn_sched_barrier(0);   // pin: gl_lds before seed
                csN = csBase[(size_t)(((tt + 2) & 31) * 2) * N_ROWS];
            }
        }
        if (PF) {   // stage A(tt+1) quarter p: harmonics 8p..8p+7
            unsigned int us[4];
            #pragma unroll
            for (int d = 0; d < 4; ++d) {
                float f0 = cur;
                float f1 = __builtin_fmaf(c2, cur, -prev);
                us[d] = pack2bf(f0, f1);
                float f2 = __builtin_fmaf(c2, f1, -cur);
                prev = f1;
                cur = f2;
            }
            const int kc = adim * 4 + p;
            *(uint4*)&Aw[arow * 64 + ((kc ^ (arow & 7)) << 3)] =
                make_uint4(us[0], us[1], us[2], us[3]);
        }
        __builtin_amdgcn_s_barrier();
        asm volatile("s_waitcnt lgkmcnt(0)" ::: "memory");
        __builtin_amdgcn_s_setprio(1);
        #pragma unroll
        for (int h = 0; h < 2; ++h)
            #pragma unroll
            for (int j = 0; j < 2; ++j)
                #pragma unroll
                for (int n = 0; n < 4; ++n)
                    acc[2 * p + j][n] = __builtin_amdgcn_mfma_f32_16x16x32_bf16(
                        af[h][j], bf[h][n], acc[2 * p + j][n], 0, 0, 0);
        __builtin_amdgcn_s_setprio(0);
        if (p < 3) {
            __builtin_amdgcn_s_barrier();
            asm volatile("" ::: "memory");
        } else if (PF) {
            // B(tt+1) 4 loads (issued p0, ~3 phases old) drained; seed(tt+2)
            // stays in flight — never vmcnt(0) in the main loop.
            asm volatile("s_waitcnt vmcnt(1)" ::: "memory");
            __builtin_amdgcn_s_barrier();
            asm volatile("" ::: "memory");
        }
    }
    if (PF) csA = csN;
}

// ---- kernel 2: fused feature-gen + bf16 MFMA GEMM, 8-phase 256^2 ----
// grid (16 row-tiles, 2 col-tiles, 8 kz) = 256 blocks x 512 thr = 1 block/CU.
// NT=64 K-tiles (BK=64 = 2 dims x 32 harmonics x 1 trig): t<32 cos, t>=32 sin.
__global__ __launch_bounds__(512, 2) void fkan_gemm(const float2* __restrict__ csT,
        const unsigned short* __restrict__ Wb, unsigned short* __restrict__ pb) {
    __shared__ unsigned short As[2][BM * 64];   // 2 x 32 KB, XOR-swizzled
    __shared__ unsigned short Bs[2][BN * 64];   // 2 x 32 KB (gl_lds dest)
    const int t = threadIdx.x;
    const int row0 = blockIdx.x * BM;
    const int col0 = blockIdx.y * BN;
    const int kz = blockIdx.z;
    const int k0 = kz * 2048;            // within-trig k offset (64 dims x 32)
    const int i0 = kz * 64;              // starting input dim for this chunk
    const int l = t & 63, wv = t >> 6;
    const int wrow = wv >> 2, wcol = wv & 3;   // wave grid 2M x 4N
    const int lm = l & 15, lq = l >> 4;
    const int swA = lm & 7;
    const int arow = t & 255, adim = t >> 8;   // A-staging unit (row, dim-half)
    // gl_lds B staging: wave wv covers cols [col0+wv*32,+32), 4 x (8col x 128B)
    const int c8 = l & 7, s8 = l >> 3;
    const unsigned short* Bg0 =
        Wb + (size_t)(col0 + wv * 32 + c8) * KT + k0 + s8 * 8;
    // B-frag read base (shorts): colgrp*512 + kseg*64 + (col&7)*8
    const int bBase = (wcol * 8 + (lm >> 3)) * 512 + lq * 64 + (lm & 7) * 8;
    const float2* csBase = csT + (size_t)(i0 + adim) * N_ROWS + row0 + arow;

    float4v acc[8][4];
    #pragma unroll
    for (int i = 0; i < 8; ++i)
        #pragma unroll
        for (int j = 0; j < 4; ++j)
            acc[i][j] = (float4v){0.f, 0.f, 0.f, 0.f};

    // ---- prologue: seed(0) -> stage A(0); gl_lds B(0); seed(1) in flight
    float2 cs0 = csBase[0];
    #pragma unroll
    for (int j = 0; j < 4; ++j)
        gl_lds16(Bg0 + (size_t)(j * 8) * KT, &Bs[0][(wv * 4 + j) * 512]);
    __builtin_amdgcn_sched_barrier(0);           // pin: gl_lds before seed load
    float2 csA = csBase[2 * N_ROWS];             // seed(1)
    stage_feats(&As[0][0], cs0, 0, arow, adim);
    asm volatile("s_waitcnt vmcnt(1) lgkmcnt(0)" ::: "memory");
    __builtin_amdgcn_s_barrier();
    asm volatile("" ::: "memory");

    #pragma unroll 1
    for (int tt = 0; tt < NT - 1; ++tt)
        gemm_tile<true>(tt, &As[tt & 1][0], &Bs[tt & 1][0],
                        &As[(tt + 1) & 1][0], &Bs[(tt + 1) & 1][0],
                        Bg0, csBase, csA, wv, wrow, lm, lq, swA, bBase,
                        arow, adim, acc);
    gemm_tile<false>(NT - 1, &As[1][0], &Bs[1][0], &As[0][0], &Bs[0][0],
                     Bg0, csBase, csA, wv, wrow, lm, lq, swA, bBase,
                     arow, adim, acc);

    // epilogue: C/D layout col=lane&15, row=quad*4+reg (m89-verified)
    unsigned short* pc = pb + (size_t)kz * N_ROWS * D_OUT;
    #pragma unroll
    for (int m = 0; m < 8; ++m)
        #pragma unroll
        for (int n = 0; n < 4; ++n)
            #pragma unroll
            for (int r = 0; r < 4; ++r) {
                const int row = row0 + wrow * 128 + m * 16 + lq * 4 + r;
                const int col = col0 + wcol * 64 + n * 16 + lm;
                pc[(size_t)row * D_OUT + col] = bf16_1(acc[m][n][r]);
            }
}

// ---- kernel 3: out = bias + sum of 8 bf16 partials (coalesced) ----
__global__ __launch_bounds__(256) void reduce_kernel(const unsigned short* __restrict__ pb,
        const float* __restrict__ bias, float* __restrict__ out) {
    const size_t e = ((size_t)blockIdx.x * 256 + threadIdx.x) * 4;
    const int col = (int)(e & (D_OUT - 1));
    float4 s = *(const float4*)(bias + col);
    #pragma unroll
    for (int c = 0; c < SPLITK; ++c) {
        ushort4 u = *(const ushort4*)(pb + (size_t)c * N_ROWS * D_OUT + e);
        union { unsigned int u; float f; } f0, f1, f2, f3;
        f0.u = (unsigned int)u.x << 16;
        f1.u = (unsigned int)u.y << 16;
        f2.u = (unsigned int)u.z << 16;
        f3.u = (unsigned int)u.w << 16;
        s.x += f0.f; s.y += f1.f; s.z += f2.f; s.w += f3.f;
    }
    *(float4*)(out + e) = s;
}

extern "C" void kernel_launch(void* const* d_in, const int* in_sizes, int n_in,
                              void* d_out, int out_size, void* d_ws, size_t ws_size,
                              hipStream_t stream) {
    const float* x    = (const float*)d_in[0];
    const float* ln_w = (const float*)d_in[1];
    const float* ln_b = (const float*)d_in[2];
    const float* fc   = (const float*)d_in[3];
    const float* bias = (const float*)d_in[4];
    float* out = (float*)d_out;

    float2* csT = (float2*)d_ws;                                        // 16 MB
    unsigned short* Wb = (unsigned short*)((char*)d_ws + (16u << 20));  // 32 MB
    unsigned short* pbp = (unsigned short*)((char*)d_ws + (48u << 20)); // 32 MB

    pre_kernel<<<256, 256, 0, stream>>>(x, ln_w, ln_b, fc, csT, Wb);
    fkan_gemm<<<dim3(N_ROWS / BM, D_OUT / BN, SPLITK), 512, 0, stream>>>(csT, Wb, pbp);
    reduce_kernel<<<2048, 256, 0, stream>>>(pbp, bias, out);            // 2.10M outs
}